// Round 8
// baseline (304.929 us; speedup 1.0000x reference)
//
#include <hip/hip_runtime.h>
#include <hip/hip_fp16.h>

// Problem constants (B=4, S=8192, IN=OUT=1024, GROUP=128)
#define K_DIM 1024
#define N_DIM 1024

typedef int v4i __attribute__((ext_vector_type(4)));

__device__ __forceinline__ void async_load16(const void* g, void* l) {
    __builtin_amdgcn_global_load_lds(
        (const __attribute__((address_space(1))) unsigned int*)g,
        (__attribute__((address_space(3))) unsigned int*)l,
        16, 0, 0);
}

// ---------------- Kernel A: fused weight prep + activation quant -----------
// Blocks [0,256): prep_w (1024 rows / 4 per block).
// Blocks [256, 256+8192): quant_x (32768 rows / 4 per block).
// ~28 us, ~roofline for its 165 MB of traffic. Unchanged (verified R4).
__global__ __launch_bounds__(256) void prep_quant(const float* __restrict__ w,
                                                  const float* __restrict__ x,
                                                  signed char* __restrict__ wq,
                                                  float* __restrict__ wscale,
                                                  signed char* __restrict__ xq,
                                                  float* __restrict__ xs) {
    const int lane = threadIdx.x & 63;
    if (blockIdx.x < 256) {
        const int row = blockIdx.x * 4 + (threadIdx.x >> 6);
        const float4* wr = (const float4*)(w + (size_t)row * K_DIM);
        float4 v[4];
#pragma unroll
        for (int j = 0; j < 4; ++j) v[j] = wr[lane * 4 + j];

        float g = 0.f;
#pragma unroll
        for (int j = 0; j < 4; ++j) {
            g = fmaxf(g, fabsf(v[j].x)); g = fmaxf(g, fabsf(v[j].y));
            g = fmaxf(g, fabsf(v[j].z)); g = fmaxf(g, fabsf(v[j].w));
        }
        g = fmaxf(g, __shfl_xor(g, 1, 64));
        g = fmaxf(g, __shfl_xor(g, 2, 64));
        g = fmaxf(g, __shfl_xor(g, 4, 64));
        const float s = __half2float(__float2half(fmaxf(g, 1e-8f)));
        float t = s;
        t += __shfl_xor(t, 8, 64);
        t += __shfl_xor(t, 16, 64);
        t += __shfl_xor(t, 32, 64);
        if (lane == 0) wscale[row] = t * 0.125f;

        int pk[4];
#pragma unroll
        for (int j = 0; j < 4; ++j) {
            const int b0 = (v[j].x > 0.f) ? 1 : -1;
            const int b1 = (v[j].y > 0.f) ? 1 : -1;
            const int b2 = (v[j].z > 0.f) ? 1 : -1;
            const int b3 = (v[j].w > 0.f) ? 1 : -1;
            pk[j] = (b0 & 255) | ((b1 & 255) << 8) | ((b2 & 255) << 16) | (b3 << 24);
        }
        *(int4*)(wq + (size_t)row * K_DIM + lane * 16) = make_int4(pk[0], pk[1], pk[2], pk[3]);
    } else {
        const int row = (blockIdx.x - 256) * 4 + (threadIdx.x >> 6);
        const float4* xr = (const float4*)(x + (size_t)row * K_DIM);
        float4 v[4];
#pragma unroll
        for (int j = 0; j < 4; ++j) v[j] = xr[lane * 4 + j];

        float am = 0.f;
#pragma unroll
        for (int j = 0; j < 4; ++j) {
            am = fmaxf(am, fabsf(v[j].x)); am = fmaxf(am, fabsf(v[j].y));
            am = fmaxf(am, fabsf(v[j].z)); am = fmaxf(am, fabsf(v[j].w));
        }
#pragma unroll
        for (int off = 32; off >= 1; off >>= 1) am = fmaxf(am, __shfl_xor(am, off, 64));
        const float scale = fmaxf(am, 1e-8f) / 127.f;
        const float inv   = 1.0f / scale;   // wave-uniform, one divide

        int pk[4];
#pragma unroll
        for (int j = 0; j < 4; ++j) {
            const int b0 = (int)fminf(fmaxf(rintf(v[j].x * inv), -128.f), 127.f);
            const int b1 = (int)fminf(fmaxf(rintf(v[j].y * inv), -128.f), 127.f);
            const int b2 = (int)fminf(fmaxf(rintf(v[j].z * inv), -128.f), 127.f);
            const int b3 = (int)fminf(fmaxf(rintf(v[j].w * inv), -128.f), 127.f);
            pk[j] = (b0 & 255) | ((b1 & 255) << 8) | ((b2 & 255) << 16) | (b3 << 24);
        }
        *(int4*)(xq + (size_t)row * K_DIM + lane * 16) = make_int4(pk[0], pk[1], pk[2], pk[3]);
        if (lane == 0) xs[row] = scale;
    }
}

// ---------------- Kernel B: int8 GEMM, barrier-free K-loop ------------------
// BM=256 x BN=128, 512 thr (8 waves: 4m x 2n), wave tile 64x64 = acc[4][4].
//
// STRUCTURE CHANGE (R7 post-mortem): five schedule variants all landed at
// 75-85 us with every pipe <16% busy -- the per-K-step barrier convoy itself
// is the invariant cost (matches learn_hip m233: stage+vmcnt+bar ~72%).
// Here the ENTIRE B panel for the block (128 wq rows x 1024 B = 128 KB) is
// staged into LDS once, then the K-loop runs with ZERO barriers and ZERO
// inline asm: per step, 4 A-frag global loads (xq is L3/L2-hot; issued by
// the compiler's own software pipeliner -- nothing blocks hoisting, LDS is
// read-only after the single sync) + 4 ds_read_b128 + 16 MFMA, fully
// unrolled over 16 steps.
//
// LDS 128 KB -> 1 block/CU (8 waves); that's fine: overlap comes from ILP,
// not TLP, and the compiler gets ~256 VGPRs of pipelining headroom.
//
// Swizzle: LDS[row][phys 16B-chunk p] = wq[row][p ^ (row&7)], applied on the
// GLOBAL source of global_load_lds (dest linear, HW rule m104) and inverted
// on ds_read (rule #21). Read conflicts: lanes r16 / r16+8 alias -> 2-way
// (free, m136); 64 lanes x 16B = optimal 8 bank-group occupancy.
__global__ __launch_bounds__(512, 2) void gemm_i8(const signed char* __restrict__ A,
                                                  const signed char* __restrict__ Bw,
                                                  const float* __restrict__ xs,
                                                  const float* __restrict__ wscale,
                                                  const float* __restrict__ bias,
                                                  float* __restrict__ out) {
    extern __shared__ __align__(16) signed char Bl[];   // [128 rows][1024 B]

    const int tid  = threadIdx.x;
    const int lane = tid & 63;
    const int wave = tid >> 6;   // 0..7
    const int wm   = wave >> 1;  // 0..3 (64-row slice of BM=256)
    const int wn   = wave & 1;   // 0..1 (64-col slice of BN=128)

    // XCD mapping: xcd = bid&7 owns 16 mT x 8 nT. A concurrent cohort on an
    // XCD is 4 mT x 8 nT -> each A panel is fetched into one XCD's L2 and
    // read by its 8 n-blocks; wq (1 MB) is L2-resident everywhere.
    const int bid = blockIdx.x;
    const int xcd = bid & 7;
    const int u   = bid >> 3;             // 0..127
    const int mT  = xcd * 16 + (u >> 3);  // 0..127
    const int nT  = u & 7;                // 0..7
    const size_t mBase = (size_t)mT * 256;
    const int    nBase = nT * 128;

    // ---- stage B panel once: call c stages rows c*8 .. c*8+7 ----
    // dest = c*8192 + tid*16 (wave-uniform base + lane*16: HW rule m104);
    // within-row phys chunk = tid&63 receives global logical chunk ^ (row&7).
    const int brow   = tid >> 6;                       // 0..7 (row within group)
    const int bchunk = (tid & 63) ^ brow;              // inverse-swizzled source
    const signed char* Bg = Bw + (size_t)(nBase + brow) * K_DIM + bchunk * 16;
#pragma unroll
    for (int c = 0; c < 16; ++c)
        async_load16(Bg + (size_t)(c * 8) * K_DIM, Bl + c * 8192 + tid * 16);

    const int r16 = lane & 15;
    const int g   = lane >> 4;     // 16B k-chunk within the 64B k-slice

    // per-lane A row bases (4 rows per lane, mf = 0..3)
    const signed char* Arow[4];
#pragma unroll
    for (int mf = 0; mf < 4; ++mf)
        Arow[mf] = A + (mBase + wm * 64 + mf * 16 + r16) * (size_t)K_DIM + g * 16;

    // per-lane B LDS byte bases (nf = 0..3); per-step phys chunk = (t*4+g)^(r16&7)
    const int s7 = r16 & 7;
    int Bbase[4];
#pragma unroll
    for (int nf = 0; nf < 4; ++nf)
        Bbase[nf] = (wn * 64 + nf * 16 + r16) * 1024;

    __syncthreads();   // the ONLY barrier: B staging complete & visible

    v4i acc[4][4] = {};

#pragma unroll
    for (int t = 0; t < 16; ++t) {
        v4i af[4], bf[4];
#pragma unroll
        for (int mf = 0; mf < 4; ++mf)
            af[mf] = *(const v4i*)(Arow[mf] + t * 64);
#pragma unroll
        for (int nf = 0; nf < 4; ++nf)
            bf[nf] = *(const v4i*)(Bl + Bbase[nf] + (((t * 4 + g) ^ s7) * 16));
#pragma unroll
        for (int mf = 0; mf < 4; ++mf)
#pragma unroll
            for (int nf = 0; nf < 4; ++nf)
                acc[mf][nf] = __builtin_amdgcn_mfma_i32_16x16x64_i8(
                    af[mf], bf[nf], acc[mf][nf], 0, 0, 0);
    }

    // epilogue: C/D layout col = lane&15, row = (lane>>4)*4 + reg
    const int rq = g * 4;
    float xsr[4][4];
#pragma unroll
    for (int mf = 0; mf < 4; ++mf)
#pragma unroll
        for (int i = 0; i < 4; ++i)
            xsr[mf][i] = xs[mBase + wm * 64 + mf * 16 + rq + i];

#pragma unroll
    for (int nf = 0; nf < 4; ++nf) {
        const int col   = nBase + wn * 64 + nf * 16 + r16;
        const float wsc = wscale[col];
        const float bb  = bias[col];
#pragma unroll
        for (int mf = 0; mf < 4; ++mf) {
#pragma unroll
            for (int i = 0; i < 4; ++i) {
                const size_t row = mBase + wm * 64 + mf * 16 + rq + i;
                out[row * N_DIM + col] = (float)acc[mf][nf][i] * xsr[mf][i] * wsc + bb;
            }
        }
    }
}

extern "C" void kernel_launch(void* const* d_in, const int* in_sizes, int n_in,
                              void* d_out, int out_size, void* d_ws, size_t ws_size,
                              hipStream_t stream) {
    const float* x    = (const float*)d_in[0];
    const float* w    = (const float*)d_in[1];
    const float* bias = (const float*)d_in[2];
    float* out = (float*)d_out;

    const int BT = in_sizes[0] / K_DIM;  // 32768 tokens

    // workspace carve
    char* ws = (char*)d_ws;
    signed char* xq     = (signed char*)ws;                                          // BT*1024 B
    float*       xs     = (float*)(ws + (size_t)BT * K_DIM);                         // BT*4 B
    signed char* wq     = (signed char*)(ws + (size_t)BT * K_DIM + (size_t)BT * 4);  // 1 MB
    float*       wscale = (float*)((char*)wq + (size_t)N_DIM * K_DIM);               // 4 KB

    static bool s_attr_set = false;
    if (!s_attr_set) {
        hipFuncSetAttribute((const void*)gemm_i8,
                            hipFuncAttributeMaxDynamicSharedMemorySize, 131072);
        s_attr_set = true;
    }

    prep_quant<<<256 + BT / 4, 256, 0, stream>>>(w, x, wq, wscale, xq, xs);
    gemm_i8<<<(BT / 256) * (N_DIM / 128), 512, 131072, stream>>>(xq, wq, xs, wscale, bias, out);
}

// Round 9
// 292.254 us; speedup vs baseline: 1.0434x; 1.0434x over previous
//
#include <hip/hip_runtime.h>
#include <hip/hip_fp16.h>

// Problem constants (B=4, S=8192, IN=OUT=1024, GROUP=128)
#define K_DIM 1024
#define N_DIM 1024

typedef int v4i __attribute__((ext_vector_type(4)));

__device__ __forceinline__ void async_load16(const void* g, void* l) {
    __builtin_amdgcn_global_load_lds(
        (const __attribute__((address_space(1))) unsigned int*)g,
        (__attribute__((address_space(3))) unsigned int*)l,
        16, 0, 0);
}

// Raw barrier: no compiler-forced vmcnt(0) drain. "memory" clobbers pin
// LDS/global *instructions*; completion is handled by explicit waitcnts.
#define BAR() do { asm volatile("" ::: "memory"); \
                   __builtin_amdgcn_s_barrier();  \
                   asm volatile("" ::: "memory"); } while (0)
#define LGKM0() do { asm volatile("s_waitcnt lgkmcnt(0)" ::: "memory"); \
                     __builtin_amdgcn_sched_barrier(0); } while (0)  // rule #18

// ---------------- Kernel A: fused weight prep + activation quant -----------
// Blocks [0,256): prep_w. Blocks [256, 256+8192): quant_x. Unchanged (R4).
__global__ __launch_bounds__(256) void prep_quant(const float* __restrict__ w,
                                                  const float* __restrict__ x,
                                                  signed char* __restrict__ wq,
                                                  float* __restrict__ wscale,
                                                  signed char* __restrict__ xq,
                                                  float* __restrict__ xs) {
    const int lane = threadIdx.x & 63;
    if (blockIdx.x < 256) {
        const int row = blockIdx.x * 4 + (threadIdx.x >> 6);
        const float4* wr = (const float4*)(w + (size_t)row * K_DIM);
        float4 v[4];
#pragma unroll
        for (int j = 0; j < 4; ++j) v[j] = wr[lane * 4 + j];

        float g = 0.f;
#pragma unroll
        for (int j = 0; j < 4; ++j) {
            g = fmaxf(g, fabsf(v[j].x)); g = fmaxf(g, fabsf(v[j].y));
            g = fmaxf(g, fabsf(v[j].z)); g = fmaxf(g, fabsf(v[j].w));
        }
        g = fmaxf(g, __shfl_xor(g, 1, 64));
        g = fmaxf(g, __shfl_xor(g, 2, 64));
        g = fmaxf(g, __shfl_xor(g, 4, 64));
        const float s = __half2float(__float2half(fmaxf(g, 1e-8f)));
        float t = s;
        t += __shfl_xor(t, 8, 64);
        t += __shfl_xor(t, 16, 64);
        t += __shfl_xor(t, 32, 64);
        if (lane == 0) wscale[row] = t * 0.125f;

        int pk[4];
#pragma unroll
        for (int j = 0; j < 4; ++j) {
            const int b0 = (v[j].x > 0.f) ? 1 : -1;
            const int b1 = (v[j].y > 0.f) ? 1 : -1;
            const int b2 = (v[j].z > 0.f) ? 1 : -1;
            const int b3 = (v[j].w > 0.f) ? 1 : -1;
            pk[j] = (b0 & 255) | ((b1 & 255) << 8) | ((b2 & 255) << 16) | (b3 << 24);
        }
        *(int4*)(wq + (size_t)row * K_DIM + lane * 16) = make_int4(pk[0], pk[1], pk[2], pk[3]);
    } else {
        const int row = (blockIdx.x - 256) * 4 + (threadIdx.x >> 6);
        const float4* xr = (const float4*)(x + (size_t)row * K_DIM);
        float4 v[4];
#pragma unroll
        for (int j = 0; j < 4; ++j) v[j] = xr[lane * 4 + j];

        float am = 0.f;
#pragma unroll
        for (int j = 0; j < 4; ++j) {
            am = fmaxf(am, fabsf(v[j].x)); am = fmaxf(am, fabsf(v[j].y));
            am = fmaxf(am, fabsf(v[j].z)); am = fmaxf(am, fabsf(v[j].w));
        }
#pragma unroll
        for (int off = 32; off >= 1; off >>= 1) am = fmaxf(am, __shfl_xor(am, off, 64));
        const float scale = fmaxf(am, 1e-8f) / 127.f;
        const float inv   = 1.0f / scale;   // wave-uniform, one divide

        int pk[4];
#pragma unroll
        for (int j = 0; j < 4; ++j) {
            const int b0 = (int)fminf(fmaxf(rintf(v[j].x * inv), -128.f), 127.f);
            const int b1 = (int)fminf(fmaxf(rintf(v[j].y * inv), -128.f), 127.f);
            const int b2 = (int)fminf(fmaxf(rintf(v[j].z * inv), -128.f), 127.f);
            const int b3 = (int)fminf(fmaxf(rintf(v[j].w * inv), -128.f), 127.f);
            pk[j] = (b0 & 255) | ((b1 & 255) << 8) | ((b2 & 255) << 16) | (b3 << 24);
        }
        *(int4*)(xq + (size_t)row * K_DIM + lane * 16) = make_int4(pk[0], pk[1], pk[2], pk[3]);
        if (lane == 0) xs[row] = scale;
    }
}

// ---------------- Kernel B: int8 GEMM, faithful 8-phase-template port ------
// 256x256 tile, BK=64, 512 thr = 8 waves (2M x 4N), wave out 128x64 =
// acc[8][4]. 16 K-tiles x 4 phases. Phase q: {2 af ds_reads (+4 bf in P0) ||
// 1 stage call of tile t+2 -> BAR -> lgkmcnt(0)+sched_barrier(0) ->
// setprio(1) -> 8 MFMA (m-frags 2q,2q+1 x nf 0..3) -> setprio(0) -> BAR}.
// Triple-buffered LDS (3 x 32 KB = 96 KB): tile t+2 staged during tile t,
// waited with COUNTED vmcnt(4) once per tile (never 0 in steady state;
// loads fly ~1 full tile ~1300 cy > HBM latency). This is the m201/m218
// combo (T3+T4+T5+T2) whose gains are regime-gated on exactly this
// fine-grained phase interleave -- never before applied faithfully here.
// Swizzle (64B rows, 4 x 16B chunks): phys_chunk = g ^ ((row>>1)&3), applied
// on the GLOBAL source of global_load_lds (dest linear tid*16, HW rule m104)
// and on ds_read addresses (rule #21). Spreads each quarter-wave's 16 lanes
// over 8 bank-quads at 2 lanes each (2-way = free, m136); the old ^(row&3)
// left 4-way conflicts.
__global__ __launch_bounds__(512, 2) void gemm_i8(const signed char* __restrict__ A,
                                                  const signed char* __restrict__ Bw,
                                                  const float* __restrict__ xs,
                                                  const float* __restrict__ wscale,
                                                  const float* __restrict__ bias,
                                                  float* __restrict__ out) {
    extern __shared__ __align__(16) signed char lds[];   // 3 x {A 16K, B 16K}

    const int tid  = threadIdx.x;
    const int lane = tid & 63;
    const int wave = tid >> 6;    // 0..7
    const int wm   = wave >> 2;   // 0..1  (128-row half)
    const int wn   = wave & 3;    // 0..3  (64-col quarter)

    // XCD mapping: xcd = bid&7 owns 16 mT x 4 nT; A-panel (256 KB) lands in
    // one XCD's L2 and is reused by its 4 n-blocks; wq (1 MB) L2-resident.
    const int bid = blockIdx.x;           // 512 blocks
    const int xcd = bid & 7;
    const int u   = bid >> 3;             // 0..63
    const int mT  = xcd * 16 + (u >> 2);  // 0..127
    const int nT  = u & 3;                // 0..3
    const size_t mBase = (size_t)mT * 256;
    const int    nBase = nT * 256;

    // staging: one call = 512 thr x 16B = 8 KB = 128 rows x 64B.
    // row = tid>>2, phys chunk = tid&3, source chunk = phys ^ ((row>>1)&3).
    const int srow = tid >> 2;                               // 0..127
    const int lc16 = ((tid & 3) ^ ((srow >> 1) & 3)) * 16;   // source col
    const int dst  = tid * 16;                               // linear LDS dest
    const signed char* Ag0 = A  + (mBase + srow) * K_DIM + lc16;
    const signed char* Ag1 = Ag0 + (size_t)128 * K_DIM;
    const signed char* Bg0 = Bw + (size_t)(nBase + srow) * K_DIM + lc16;
    const signed char* Bg1 = Bg0 + (size_t)128 * K_DIM;

#define SA0(b, kt) async_load16(Ag0 + (kt) * 64, lds + (b) * 32768 + dst)
#define SA1(b, kt) async_load16(Ag1 + (kt) * 64, lds + (b) * 32768 + 8192 + dst)
#define SB0(b, kt) async_load16(Bg0 + (kt) * 64, lds + (b) * 32768 + 16384 + dst)
#define SB1(b, kt) async_load16(Bg1 + (kt) * 64, lds + (b) * 32768 + 24576 + dst)

    // fragment LDS offsets (per-lane constants; add buf base at use)
    const int r16  = lane & 15;
    const int g    = lane >> 4;                       // 16B k-chunk 0..3
    const int phys = (g ^ ((r16 >> 1) & 3)) * 16;     // swizzled chunk offset
    int aoff[8], boff[4];
#pragma unroll
    for (int mf = 0; mf < 8; ++mf)
        aoff[mf] = (wm * 128 + mf * 16 + r16) * 64 + phys;
#pragma unroll
    for (int nf = 0; nf < 4; ++nf)
        boff[nf] = 16384 + (wn * 64 + nf * 16 + r16) * 64 + phys;

    v4i acc[8][4] = {};

    // prologue: stage tiles 0 and 1; wait tile 0 only (tile 1 stays in flight)
    SA0(0, 0); SA1(0, 0); SB0(0, 0); SB1(0, 0);
    SA0(1, 1); SA1(1, 1); SB0(1, 1); SB1(1, 1);
    asm volatile("s_waitcnt vmcnt(4)" ::: "memory");
    BAR();

    for (int t = 0; t < 16; ++t) {
        const signed char* Lb = lds + (t % 3) * 32768;
        const int bn = (t + 2) % 3;
        const bool st = (t < 14);
        v4i bf[4], af0, af1;

        // ---- Phase 0: bf[0..3] + af[0..1]; stage A-half0 of t+2 ----
#pragma unroll
        for (int nf = 0; nf < 4; ++nf) bf[nf] = *(const v4i*)(Lb + boff[nf]);
        af0 = *(const v4i*)(Lb + aoff[0]);
        af1 = *(const v4i*)(Lb + aoff[1]);
        if (st) SA0(bn, t + 2);
        BAR(); LGKM0();
        __builtin_amdgcn_s_setprio(1);
#pragma unroll
        for (int nf = 0; nf < 4; ++nf) {
            acc[0][nf] = __builtin_amdgcn_mfma_i32_16x16x64_i8(af0, bf[nf], acc[0][nf], 0, 0, 0);
            acc[1][nf] = __builtin_amdgcn_mfma_i32_16x16x64_i8(af1, bf[nf], acc[1][nf], 0, 0, 0);
        }
        __builtin_amdgcn_s_setprio(0);
        BAR();

        // ---- Phase 1: af[2..3]; stage A-half1 ----
        af0 = *(const v4i*)(Lb + aoff[2]);
        af1 = *(const v4i*)(Lb + aoff[3]);
        if (st) SA1(bn, t + 2);
        BAR(); LGKM0();
        __builtin_amdgcn_s_setprio(1);
#pragma unroll
        for (int nf = 0; nf < 4; ++nf) {
            acc[2][nf] = __builtin_amdgcn_mfma_i32_16x16x64_i8(af0, bf[nf], acc[2][nf], 0, 0, 0);
            acc[3][nf] = __builtin_amdgcn_mfma_i32_16x16x64_i8(af1, bf[nf], acc[3][nf], 0, 0, 0);
        }
        __builtin_amdgcn_s_setprio(0);
        BAR();

        // ---- Phase 2: af[4..5]; stage B-half0 ----
        af0 = *(const v4i*)(Lb + aoff[4]);
        af1 = *(const v4i*)(Lb + aoff[5]);
        if (st) SB0(bn, t + 2);
        BAR(); LGKM0();
        __builtin_amdgcn_s_setprio(1);
#pragma unroll
        for (int nf = 0; nf < 4; ++nf) {
            acc[4][nf] = __builtin_amdgcn_mfma_i32_16x16x64_i8(af0, bf[nf], acc[4][nf], 0, 0, 0);
            acc[5][nf] = __builtin_amdgcn_mfma_i32_16x16x64_i8(af1, bf[nf], acc[5][nf], 0, 0, 0);
        }
        __builtin_amdgcn_s_setprio(0);
        BAR();

        // ---- Phase 3: af[6..7]; stage B-half1; counted vmcnt per tile ----
        af0 = *(const v4i*)(Lb + aoff[6]);
        af1 = *(const v4i*)(Lb + aoff[7]);
        if (st) SB1(bn, t + 2);
        BAR(); LGKM0();
        __builtin_amdgcn_s_setprio(1);
#pragma unroll
        for (int nf = 0; nf < 4; ++nf) {
            acc[6][nf] = __builtin_amdgcn_mfma_i32_16x16x64_i8(af0, bf[nf], acc[6][nf], 0, 0, 0);
            acc[7][nf] = __builtin_amdgcn_mfma_i32_16x16x64_i8(af1, bf[nf], acc[7][nf], 0, 0, 0);
        }
        __builtin_amdgcn_s_setprio(0);
        // tile t+1 must be landed before anyone reads it after this barrier;
        // steady state: 8 in flight (t+1:4 oldest, t+2:4) -> vmcnt(4).
        if (t < 14) asm volatile("s_waitcnt vmcnt(4)" ::: "memory");
        else        asm volatile("s_waitcnt vmcnt(0)" ::: "memory");
        BAR();
    }
#undef SA0
#undef SA1
#undef SB0
#undef SB1

    // epilogue: C/D layout col = lane&15, row = (lane>>4)*4 + reg
    const int rq = g * 4;
    float xsr[8][4];
#pragma unroll
    for (int mf = 0; mf < 8; ++mf)
#pragma unroll
        for (int i = 0; i < 4; ++i)
            xsr[mf][i] = xs[mBase + wm * 128 + mf * 16 + rq + i];

#pragma unroll
    for (int nf = 0; nf < 4; ++nf) {
        const int col   = nBase + wn * 64 + nf * 16 + r16;
        const float wsc = wscale[col];
        const float bb  = bias[col];
#pragma unroll
        for (int mf = 0; mf < 8; ++mf) {
#pragma unroll
            for (int i = 0; i < 4; ++i) {
                const size_t row = mBase + wm * 128 + mf * 16 + rq + i;
                out[row * N_DIM + col] = (float)acc[mf][nf][i] * xsr[mf][i] * wsc + bb;
            }
        }
    }
}

extern "C" void kernel_launch(void* const* d_in, const int* in_sizes, int n_in,
                              void* d_out, int out_size, void* d_ws, size_t ws_size,
                              hipStream_t stream) {
    const float* x    = (const float*)d_in[0];
    const float* w    = (const float*)d_in[1];
    const float* bias = (const float*)d_in[2];
    float* out = (float*)d_out;

    const int BT = in_sizes[0] / K_DIM;  // 32768 tokens

    // workspace carve
    char* ws = (char*)d_ws;
    signed char* xq     = (signed char*)ws;                                          // BT*1024 B
    float*       xs     = (float*)(ws + (size_t)BT * K_DIM);                         // BT*4 B
    signed char* wq     = (signed char*)(ws + (size_t)BT * K_DIM + (size_t)BT * 4);  // 1 MB
    float*       wscale = (float*)((char*)wq + (size_t)N_DIM * K_DIM);               // 4 KB

    static bool s_attr_set = false;
    if (!s_attr_set) {
        hipFuncSetAttribute((const void*)gemm_i8,
                            hipFuncAttributeMaxDynamicSharedMemorySize, 98304);
        s_attr_set = true;
    }

    prep_quant<<<256 + BT / 4, 256, 0, stream>>>(w, x, wq, wscale, xq, xs);
    gemm_i8<<<(BT / 256) * (N_DIM / 256), 512, 98304, stream>>>(xq, wq, xs, wscale, bias, out);
}

// Round 10
// 275.253 us; speedup vs baseline: 1.1078x; 1.0618x over previous
//
#include <hip/hip_runtime.h>
#include <hip/hip_fp16.h>

// Problem constants (B=4, S=8192, IN=OUT=1024, GROUP=128)
#define K_DIM 1024
#define N_DIM 1024

typedef int v4i __attribute__((ext_vector_type(4)));

__device__ __forceinline__ void async_load16(const void* g, void* l) {
    __builtin_amdgcn_global_load_lds(
        (const __attribute__((address_space(1))) unsigned int*)g,
        (__attribute__((address_space(3))) unsigned int*)l,
        16, 0, 0);
}

// Raw barrier: no compiler-forced vmcnt(0) drain. "memory" clobbers pin
// LDS/global *instructions*; completion is handled by explicit waitcnts.
#define BAR() do { asm volatile("" ::: "memory"); \
                   __builtin_amdgcn_s_barrier();  \
                   asm volatile("" ::: "memory"); } while (0)
#define LGKM0() do { asm volatile("s_waitcnt lgkmcnt(0)" ::: "memory"); \
                     __builtin_amdgcn_sched_barrier(0); } while (0)  // rule #18

// ---------------- Kernel A: fused weight prep + activation quant -----------
// Blocks [0,256): prep_w. Blocks [256, 256+8192): quant_x. Unchanged (R4).
__global__ __launch_bounds__(256) void prep_quant(const float* __restrict__ w,
                                                  const float* __restrict__ x,
                                                  signed char* __restrict__ wq,
                                                  float* __restrict__ wscale,
                                                  signed char* __restrict__ xq,
                                                  float* __restrict__ xs) {
    const int lane = threadIdx.x & 63;
    if (blockIdx.x < 256) {
        const int row = blockIdx.x * 4 + (threadIdx.x >> 6);
        const float4* wr = (const float4*)(w + (size_t)row * K_DIM);
        float4 v[4];
#pragma unroll
        for (int j = 0; j < 4; ++j) v[j] = wr[lane * 4 + j];

        float g = 0.f;
#pragma unroll
        for (int j = 0; j < 4; ++j) {
            g = fmaxf(g, fabsf(v[j].x)); g = fmaxf(g, fabsf(v[j].y));
            g = fmaxf(g, fabsf(v[j].z)); g = fmaxf(g, fabsf(v[j].w));
        }
        g = fmaxf(g, __shfl_xor(g, 1, 64));
        g = fmaxf(g, __shfl_xor(g, 2, 64));
        g = fmaxf(g, __shfl_xor(g, 4, 64));
        const float s = __half2float(__float2half(fmaxf(g, 1e-8f)));
        float t = s;
        t += __shfl_xor(t, 8, 64);
        t += __shfl_xor(t, 16, 64);
        t += __shfl_xor(t, 32, 64);
        if (lane == 0) wscale[row] = t * 0.125f;

        int pk[4];
#pragma unroll
        for (int j = 0; j < 4; ++j) {
            const int b0 = (v[j].x > 0.f) ? 1 : -1;
            const int b1 = (v[j].y > 0.f) ? 1 : -1;
            const int b2 = (v[j].z > 0.f) ? 1 : -1;
            const int b3 = (v[j].w > 0.f) ? 1 : -1;
            pk[j] = (b0 & 255) | ((b1 & 255) << 8) | ((b2 & 255) << 16) | (b3 << 24);
        }
        *(int4*)(wq + (size_t)row * K_DIM + lane * 16) = make_int4(pk[0], pk[1], pk[2], pk[3]);
    } else {
        const int row = (blockIdx.x - 256) * 4 + (threadIdx.x >> 6);
        const float4* xr = (const float4*)(x + (size_t)row * K_DIM);
        float4 v[4];
#pragma unroll
        for (int j = 0; j < 4; ++j) v[j] = xr[lane * 4 + j];

        float am = 0.f;
#pragma unroll
        for (int j = 0; j < 4; ++j) {
            am = fmaxf(am, fabsf(v[j].x)); am = fmaxf(am, fabsf(v[j].y));
            am = fmaxf(am, fabsf(v[j].z)); am = fmaxf(am, fabsf(v[j].w));
        }
#pragma unroll
        for (int off = 32; off >= 1; off >>= 1) am = fmaxf(am, __shfl_xor(am, off, 64));
        const float scale = fmaxf(am, 1e-8f) / 127.f;
        const float inv   = 1.0f / scale;   // wave-uniform, one divide

        int pk[4];
#pragma unroll
        for (int j = 0; j < 4; ++j) {
            const int b0 = (int)fminf(fmaxf(rintf(v[j].x * inv), -128.f), 127.f);
            const int b1 = (int)fminf(fmaxf(rintf(v[j].y * inv), -128.f), 127.f);
            const int b2 = (int)fminf(fmaxf(rintf(v[j].z * inv), -128.f), 127.f);
            const int b3 = (int)fminf(fmaxf(rintf(v[j].w * inv), -128.f), 127.f);
            pk[j] = (b0 & 255) | ((b1 & 255) << 8) | ((b2 & 255) << 16) | (b3 << 24);
        }
        *(int4*)(xq + (size_t)row * K_DIM + lane * 16) = make_int4(pk[0], pk[1], pk[2], pk[3]);
        if (lane == 0) xs[row] = scale;
    }
}

// ---------------- Kernel B: int8 GEMM, 2-fat-phase schedule ----------------
// 256x256 tile, BK=64, 512 thr = 8 waves (2M x 4N), wave out 128x64 =
// acc[8][4]. 16 K-tiles x 2 PHASES (merged from R9's 4: phases were too
// thin -- 8 MFMA (~163 SIMD-cy) per barrier-pair vs the m201 template's 16
// (~320 cy); at 2 waves/SIMD the barrier overhead was ~40% of each phase).
//   Phase A: {bf[0..3]+af[0..3] ds_reads || stage A-halves of t+2} ->
//            BAR -> lgkm0 -> setprio(1) -> 16 MFMA (mf 0..3) -> setprio(0) -> BAR
//   Phase B: {af[4..7] ds_reads || stage B-halves of t+2} ->
//            BAR -> lgkm0 -> setprio(1) -> 16 MFMA (mf 4..7) -> setprio(0) ->
//            counted vmcnt(4) -> BAR
// Triple-buffered LDS (3 x 32 KB): tile t+2 staged during t; vmcnt(4) once
// per tile waits only tile t+1's 4 calls (issued a full tile ago, ~1300 cy
// in flight > HBM latency); never 0 in steady state. Barriers 8->4 per tile.
// Swizzle: phys chunk = g ^ ((row>>1)&3) on the GLOBAL source of
// global_load_lds (dest linear tid*16, HW rule m104) and on ds_read (rule
// #21): quarter-wave's 16 lanes spread over 8 bank-quads at 2-way (free).
// Epilogue: NONTEMPORAL C stores -- write-once data, keeps L2 clean for the
// A/B panel reads and shortens the end-of-kernel write drain.
__global__ __launch_bounds__(512, 2) void gemm_i8(const signed char* __restrict__ A,
                                                  const signed char* __restrict__ Bw,
                                                  const float* __restrict__ xs,
                                                  const float* __restrict__ wscale,
                                                  const float* __restrict__ bias,
                                                  float* __restrict__ out) {
    extern __shared__ __align__(16) signed char lds[];   // 3 x {A 16K, B 16K}

    const int tid  = threadIdx.x;
    const int lane = tid & 63;
    const int wave = tid >> 6;    // 0..7
    const int wm   = wave >> 2;   // 0..1  (128-row half)
    const int wn   = wave & 3;    // 0..3  (64-col quarter)

    // XCD mapping: xcd = bid&7 owns 16 mT x 4 nT; A-panel (256 KB) lands in
    // one XCD's L2 and is reused by its 4 n-blocks; wq (1 MB) L2-resident.
    const int bid = blockIdx.x;           // 512 blocks
    const int xcd = bid & 7;
    const int u   = bid >> 3;             // 0..63
    const int mT  = xcd * 16 + (u >> 2);  // 0..127
    const int nT  = u & 3;                // 0..3
    const size_t mBase = (size_t)mT * 256;
    const int    nBase = nT * 256;

    // staging: one call = 512 thr x 16B = 8 KB = 128 rows x 64B.
    // row = tid>>2, phys chunk = tid&3, source chunk = phys ^ ((row>>1)&3).
    const int srow = tid >> 2;                               // 0..127
    const int lc16 = ((tid & 3) ^ ((srow >> 1) & 3)) * 16;   // source col
    const int dst  = tid * 16;                               // linear LDS dest
    const signed char* Ag0 = A  + (mBase + srow) * K_DIM + lc16;
    const signed char* Ag1 = Ag0 + (size_t)128 * K_DIM;
    const signed char* Bg0 = Bw + (size_t)(nBase + srow) * K_DIM + lc16;
    const signed char* Bg1 = Bg0 + (size_t)128 * K_DIM;

#define SA0(b, kt) async_load16(Ag0 + (kt) * 64, lds + (b) * 32768 + dst)
#define SA1(b, kt) async_load16(Ag1 + (kt) * 64, lds + (b) * 32768 + 8192 + dst)
#define SB0(b, kt) async_load16(Bg0 + (kt) * 64, lds + (b) * 32768 + 16384 + dst)
#define SB1(b, kt) async_load16(Bg1 + (kt) * 64, lds + (b) * 32768 + 24576 + dst)

    // fragment LDS offsets (per-lane constants; add buf base at use)
    const int r16  = lane & 15;
    const int g    = lane >> 4;                       // 16B k-chunk 0..3
    const int phys = (g ^ ((r16 >> 1) & 3)) * 16;     // swizzled chunk offset
    int aoff[8], boff[4];
#pragma unroll
    for (int mf = 0; mf < 8; ++mf)
        aoff[mf] = (wm * 128 + mf * 16 + r16) * 64 + phys;
#pragma unroll
    for (int nf = 0; nf < 4; ++nf)
        boff[nf] = 16384 + (wn * 64 + nf * 16 + r16) * 64 + phys;

    v4i acc[8][4] = {};

    // prologue: stage tiles 0 and 1; wait tile 0 only (tile 1 stays in flight)
    SA0(0, 0); SA1(0, 0); SB0(0, 0); SB1(0, 0);
    SA0(1, 1); SA1(1, 1); SB0(1, 1); SB1(1, 1);
    asm volatile("s_waitcnt vmcnt(4)" ::: "memory");
    BAR();

    for (int t = 0; t < 16; ++t) {
        const signed char* Lb = lds + (t % 3) * 32768;
        const int bn = (t + 2) % 3;
        const bool st = (t < 14);
        v4i bf[4], af[4];

        // ---- Phase A: bf[0..3]+af[0..3]; stage A halves of t+2; 16 MFMA ----
#pragma unroll
        for (int nf = 0; nf < 4; ++nf) bf[nf] = *(const v4i*)(Lb + boff[nf]);
#pragma unroll
        for (int mf = 0; mf < 4; ++mf) af[mf] = *(const v4i*)(Lb + aoff[mf]);
        if (st) { SA0(bn, t + 2); SA1(bn, t + 2); }
        BAR(); LGKM0();
        __builtin_amdgcn_s_setprio(1);
#pragma unroll
        for (int mf = 0; mf < 4; ++mf)
#pragma unroll
            for (int nf = 0; nf < 4; ++nf)
                acc[mf][nf] = __builtin_amdgcn_mfma_i32_16x16x64_i8(
                    af[mf], bf[nf], acc[mf][nf], 0, 0, 0);
        __builtin_amdgcn_s_setprio(0);
        BAR();

        // ---- Phase B: af[4..7]; stage B halves of t+2; 16 MFMA; counted wait
#pragma unroll
        for (int mf = 0; mf < 4; ++mf) af[mf] = *(const v4i*)(Lb + aoff[4 + mf]);
        if (st) { SB0(bn, t + 2); SB1(bn, t + 2); }
        BAR(); LGKM0();
        __builtin_amdgcn_s_setprio(1);
#pragma unroll
        for (int mf = 0; mf < 4; ++mf)
#pragma unroll
            for (int nf = 0; nf < 4; ++nf)
                acc[4 + mf][nf] = __builtin_amdgcn_mfma_i32_16x16x64_i8(
                    af[mf], bf[nf], acc[4 + mf][nf], 0, 0, 0);
        __builtin_amdgcn_s_setprio(0);
        // tile t+1 must be landed before anyone reads it after this barrier;
        // steady state: 8 in flight (t+1:4 oldest, t+2:4) -> vmcnt(4).
        if (t < 14) asm volatile("s_waitcnt vmcnt(4)" ::: "memory");
        else        asm volatile("s_waitcnt vmcnt(0)" ::: "memory");
        BAR();
    }
#undef SA0
#undef SA1
#undef SB0
#undef SB1

    // epilogue: C/D layout col = lane&15, row = (lane>>4)*4 + reg.
    // Nontemporal: C is write-once, never re-read by this grid.
    const int rq = g * 4;
    float xsr[8][4];
#pragma unroll
    for (int mf = 0; mf < 8; ++mf)
#pragma unroll
        for (int i = 0; i < 4; ++i)
            xsr[mf][i] = xs[mBase + wm * 128 + mf * 16 + rq + i];

#pragma unroll
    for (int nf = 0; nf < 4; ++nf) {
        const int col   = nBase + wn * 64 + nf * 16 + r16;
        const float wsc = wscale[col];
        const float bb  = bias[col];
#pragma unroll
        for (int mf = 0; mf < 8; ++mf) {
#pragma unroll
            for (int i = 0; i < 4; ++i) {
                const size_t row = mBase + wm * 128 + mf * 16 + rq + i;
                __builtin_nontemporal_store(
                    (float)acc[mf][nf][i] * xsr[mf][i] * wsc + bb,
                    out + row * N_DIM + col);
            }
        }
    }
}

extern "C" void kernel_launch(void* const* d_in, const int* in_sizes, int n_in,
                              void* d_out, int out_size, void* d_ws, size_t ws_size,
                              hipStream_t stream) {
    const float* x    = (const float*)d_in[0];
    const float* w    = (const float*)d_in[1];
    const float* bias = (const float*)d_in[2];
    float* out = (float*)d_out;

    const int BT = in_sizes[0] / K_DIM;  // 32768 tokens

    // workspace carve
    char* ws = (char*)d_ws;
    signed char* xq     = (signed char*)ws;                                          // BT*1024 B
    float*       xs     = (float*)(ws + (size_t)BT * K_DIM);                         // BT*4 B
    signed char* wq     = (signed char*)(ws + (size_t)BT * K_DIM + (size_t)BT * 4);  // 1 MB
    float*       wscale = (float*)((char*)wq + (size_t)N_DIM * K_DIM);               // 4 KB

    static bool s_attr_set = false;
    if (!s_attr_set) {
        hipFuncSetAttribute((const void*)gemm_i8,
                            hipFuncAttributeMaxDynamicSharedMemorySize, 98304);
        s_attr_set = true;
    }

    prep_quant<<<256 + BT / 4, 256, 0, stream>>>(w, x, wq, wscale, xq, xs);
    gemm_i8<<<(BT / 256) * (N_DIM / 256), 512, 98304, stream>>>(xq, wq, xs, wscale, bias, out);
}

// Round 11
// 274.575 us; speedup vs baseline: 1.1105x; 1.0025x over previous
//
#include <hip/hip_runtime.h>
#include <hip/hip_fp16.h>

// Problem constants (B=4, S=8192, IN=OUT=1024, GROUP=128)
#define K_DIM 1024
#define N_DIM 1024

typedef int v4i __attribute__((ext_vector_type(4)));

__device__ __forceinline__ void async_load16(const void* g, void* l) {
    __builtin_amdgcn_global_load_lds(
        (const __attribute__((address_space(1))) unsigned int*)g,
        (__attribute__((address_space(3))) unsigned int*)l,
        16, 0, 0);
}

// Raw barrier: no compiler-forced vmcnt(0) drain. "memory" clobbers pin
// LDS/global *instructions* (completion is handled by explicit waitcnts).
#define BAR() do { asm volatile("" ::: "memory"); \
                   __builtin_amdgcn_s_barrier();  \
                   asm volatile("" ::: "memory"); } while (0)

// ---------------- Kernel A: fused weight prep + activation quant -----------
// Blocks [0,256): prep_w (1024 rows / 4 per block).
// Blocks [256, 256+8192): quant_x (32768 rows / 4 per block).
// ~28 us, ~roofline for its 165 MB of traffic (floor ~26 us at 6.3 TB/s).
__global__ __launch_bounds__(256) void prep_quant(const float* __restrict__ w,
                                                  const float* __restrict__ x,
                                                  signed char* __restrict__ wq,
                                                  float* __restrict__ wscale,
                                                  signed char* __restrict__ xq,
                                                  float* __restrict__ xs) {
    const int lane = threadIdx.x & 63;
    if (blockIdx.x < 256) {
        const int row = blockIdx.x * 4 + (threadIdx.x >> 6);
        const float4* wr = (const float4*)(w + (size_t)row * K_DIM);
        float4 v[4];
#pragma unroll
        for (int j = 0; j < 4; ++j) v[j] = wr[lane * 4 + j];

        float g = 0.f;
#pragma unroll
        for (int j = 0; j < 4; ++j) {
            g = fmaxf(g, fabsf(v[j].x)); g = fmaxf(g, fabsf(v[j].y));
            g = fmaxf(g, fabsf(v[j].z)); g = fmaxf(g, fabsf(v[j].w));
        }
        g = fmaxf(g, __shfl_xor(g, 1, 64));
        g = fmaxf(g, __shfl_xor(g, 2, 64));
        g = fmaxf(g, __shfl_xor(g, 4, 64));
        const float s = __half2float(__float2half(fmaxf(g, 1e-8f)));
        float t = s;
        t += __shfl_xor(t, 8, 64);
        t += __shfl_xor(t, 16, 64);
        t += __shfl_xor(t, 32, 64);
        if (lane == 0) wscale[row] = t * 0.125f;

        int pk[4];
#pragma unroll
        for (int j = 0; j < 4; ++j) {
            const int b0 = (v[j].x > 0.f) ? 1 : -1;
            const int b1 = (v[j].y > 0.f) ? 1 : -1;
            const int b2 = (v[j].z > 0.f) ? 1 : -1;
            const int b3 = (v[j].w > 0.f) ? 1 : -1;
            pk[j] = (b0 & 255) | ((b1 & 255) << 8) | ((b2 & 255) << 16) | (b3 << 24);
        }
        *(int4*)(wq + (size_t)row * K_DIM + lane * 16) = make_int4(pk[0], pk[1], pk[2], pk[3]);
    } else {
        const int row = (blockIdx.x - 256) * 4 + (threadIdx.x >> 6);
        const float4* xr = (const float4*)(x + (size_t)row * K_DIM);
        float4 v[4];
#pragma unroll
        for (int j = 0; j < 4; ++j) v[j] = xr[lane * 4 + j];

        float am = 0.f;
#pragma unroll
        for (int j = 0; j < 4; ++j) {
            am = fmaxf(am, fabsf(v[j].x)); am = fmaxf(am, fabsf(v[j].y));
            am = fmaxf(am, fabsf(v[j].z)); am = fmaxf(am, fabsf(v[j].w));
        }
#pragma unroll
        for (int off = 32; off >= 1; off >>= 1) am = fmaxf(am, __shfl_xor(am, off, 64));
        const float scale = fmaxf(am, 1e-8f) / 127.f;
        const float inv   = 1.0f / scale;   // wave-uniform, one divide

        int pk[4];
#pragma unroll
        for (int j = 0; j < 4; ++j) {
            const int b0 = (int)fminf(fmaxf(rintf(v[j].x * inv), -128.f), 127.f);
            const int b1 = (int)fminf(fmaxf(rintf(v[j].y * inv), -128.f), 127.f);
            const int b2 = (int)fminf(fmaxf(rintf(v[j].z * inv), -128.f), 127.f);
            const int b3 = (int)fminf(fmaxf(rintf(v[j].w * inv), -128.f), 127.f);
            pk[j] = (b0 & 255) | ((b1 & 255) << 8) | ((b2 & 255) << 16) | (b3 << 24);
        }
        *(int4*)(xq + (size_t)row * K_DIM + lane * 16) = make_int4(pk[0], pk[1], pk[2], pk[3]);
        if (lane == 0) xs[row] = scale;
    }
}

// ---------------- Kernel B: int8 GEMM (session-best R4 configuration) ------
// 128x128 tile, 256 thr (4 waves 2x2), wave tile 64x64 = acc[4][4], BK=64.
// LDS: 2 x (128x64) x {A,B} = 32 KiB; __launch_bounds__(256,4) -> 4 blocks/CU.
// Per K-step: vmcnt(0) -> barrier -> STAGE(t+1, other buf) -> ds_read+MFMA(t)
// -> sched_barrier(0) -> lgkmcnt(0). Stage issued EARLY, waited one full
// compute phase later.
// Session conclusion (10 rounds, 7 structures, all 75-91 us): this GEMM sits
// at a latency-structure plateau -- MfmaUtil 12-16%, VALUBusy 9-14%, HBM
// <25%, conflicts ~0 in every measured profile; time invariant to barrier
// count, pipeline depth, LDS traffic, occupancy, and phase granularity.
// STAGING HW RULE (m104/m108): LDS dest = wave-uniform base + lane*16 ->
// dest tid*16, 4KB/call = 64 rows x 64B; row = tid>>2, phys chunk = tid&3.
// Swizzle: phys chunk = logical chunk ^ (row&3) applied on the GLOBAL source
// (dest linear) and on ds_read addresses -- same involution (rule #21).
__global__ __launch_bounds__(256, 4) void gemm_i8(const signed char* __restrict__ A,
                                                  const signed char* __restrict__ Bw,
                                                  const float* __restrict__ xs,
                                                  const float* __restrict__ wscale,
                                                  const float* __restrict__ bias,
                                                  float* __restrict__ out) {
    __shared__ __align__(16) signed char As[2][128 * 64];
    __shared__ __align__(16) signed char Bs[2][128 * 64];

    const int tid  = threadIdx.x;
    const int lane = tid & 63;
    const int wave = tid >> 6;
    const int wm = wave >> 1;   // 0..1
    const int wn = wave & 1;    // 0..1

    // XCD-aware mapping: XCD owns 32 m-tiles x 8 n-tiles so an A-panel lands
    // in one XCD's L2 and is reused for all 8 n-tiles.
    const int bid = blockIdx.x;
    const int xcd = bid & 7;
    const int q   = bid >> 3;            // 0..255
    const int mT  = xcd * 32 + (q >> 3); // 0..255
    const int nT  = q & 7;
    const size_t mBase = (size_t)mT * 128;
    const int    nBase = nT * 128;

    // staging: row = tid>>2, phys chunk = tid&3, source col inverse-swizzled.
    const int srow = tid >> 2;                              // 0..63
    const int scol = ((tid & 3) ^ (srow & 3)) * 16;         // logical source col
    const int soff = tid * 16;                              // linear LDS dest
    const signed char* Ag = A  + (mBase + srow) * K_DIM + scol;
    const signed char* Bg = Bw + (size_t)(nBase + srow) * K_DIM + scol;

#define STAGE(b, kt) do {                                                \
        const int _ko = (kt) * 64;                                       \
        async_load16(Ag + _ko,                      As[b] + soff);       \
        async_load16(Ag + (size_t)64 * K_DIM + _ko, As[b] + 4096 + soff);\
        async_load16(Bg + _ko,                      Bs[b] + soff);       \
        async_load16(Bg + (size_t)64 * K_DIM + _ko, Bs[b] + 4096 + soff);\
    } while (0)

    v4i acc[4][4] = {};
    const int r16 = lane & 15;
    const int g   = lane >> 4;                 // logical 16B k-chunk, 0..3
    const int co  = (g ^ (r16 & 3)) * 16;      // swizzled phys offset

    STAGE(0, 0);

    for (int t = 0; t < 16; ++t) {
        // tile t's 4 loads are the only outstanding VMEM ops; issued one full
        // compute phase ago (prologue for t=0).
        asm volatile("s_waitcnt vmcnt(0)" ::: "memory");
        BAR();
        if (t < 15) STAGE((t + 1) & 1, t + 1);   // into buffer last read at t-1

        const signed char* Ab = As[t & 1];
        const signed char* Bb = Bs[t & 1];
        v4i af[4], bf[4];
#pragma unroll
        for (int mf = 0; mf < 4; ++mf)
            af[mf] = *(const v4i*)(Ab + ((wm * 64 + mf * 16 + r16) << 6) + co);
#pragma unroll
        for (int nf = 0; nf < 4; ++nf)
            bf[nf] = *(const v4i*)(Bb + ((wn * 64 + nf * 16 + r16) << 6) + co);

#pragma unroll
        for (int mf = 0; mf < 4; ++mf)
#pragma unroll
            for (int nf = 0; nf < 4; ++nf)
                acc[mf][nf] = __builtin_amdgcn_mfma_i32_16x16x64_i8(
                    af[mf], bf[nf], acc[mf][nf], 0, 0, 0);

        // pin instruction order (rule #18), then require this wave's ds_reads
        // complete before it can cross the next barrier (after which other
        // waves' staging overwrites the other buffer).
        __builtin_amdgcn_sched_barrier(0);
        asm volatile("s_waitcnt lgkmcnt(0)" ::: "memory");
    }
#undef STAGE

    // epilogue: C/D layout col = lane&15, row = (lane>>4)*4 + reg
    const int cc = r16;
    const int rq = (lane >> 4) * 4;
    float xsr[4][4];   // loaded post-loop: no register lifetime across K-loop
#pragma unroll
    for (int mf = 0; mf < 4; ++mf)
#pragma unroll
        for (int i = 0; i < 4; ++i)
            xsr[mf][i] = xs[mBase + wm * 64 + mf * 16 + rq + i];

#pragma unroll
    for (int nf = 0; nf < 4; ++nf) {
        const int col   = nBase + wn * 64 + nf * 16 + cc;
        const float wsc = wscale[col];
        const float bb  = bias[col];
#pragma unroll
        for (int mf = 0; mf < 4; ++mf) {
#pragma unroll
            for (int i = 0; i < 4; ++i) {
                const size_t row = mBase + wm * 64 + mf * 16 + rq + i;
                out[row * N_DIM + col] = (float)acc[mf][nf][i] * xsr[mf][i] * wsc + bb;
            }
        }
    }
}

extern "C" void kernel_launch(void* const* d_in, const int* in_sizes, int n_in,
                              void* d_out, int out_size, void* d_ws, size_t ws_size,
                              hipStream_t stream) {
    const float* x    = (const float*)d_in[0];
    const float* w    = (const float*)d_in[1];
    const float* bias = (const float*)d_in[2];
    float* out = (float*)d_out;

    const int BT = in_sizes[0] / K_DIM;  // 32768 tokens

    // workspace carve
    char* ws = (char*)d_ws;
    signed char* xq     = (signed char*)ws;                                          // BT*1024 B
    float*       xs     = (float*)(ws + (size_t)BT * K_DIM);                         // BT*4 B
    signed char* wq     = (signed char*)(ws + (size_t)BT * K_DIM + (size_t)BT * 4);  // 1 MB
    float*       wscale = (float*)((char*)wq + (size_t)N_DIM * K_DIM);               // 4 KB

    prep_quant<<<256 + BT / 4, 256, 0, stream>>>(w, x, wq, wscale, xq, xs);
    gemm_i8<<<(BT / 128) * (N_DIM / 128), 256, 0, stream>>>(xq, wq, xs, wscale, bias, out);
}